// Round 1
// baseline (206.912 us; speedup 1.0000x reference)
//
#include <hip/hip_runtime.h>
#include <hip/hip_bf16.h>
#include <stdint.h>

// Router: logits = x @ wg^T + gr @ gm^T ; std-normalized softmax; top-2;
// zero expert 7; renormalize. Outputs flat: gates[T,2] | indices[T,2] (as
// float) | logits[T,8].
//
// Memory-bound on x (128 MiB fp32). One wave = 8 tokens, lane = 4-float
// column slice, coalesced dwordx4 streams. wg stays in L1/L2 (64 KB).

#define WAVES_PER_BLOCK 4
#define TOKENS_PER_WAVE 8
#define TOKENS_PER_BLOCK (WAVES_PER_BLOCK * TOKENS_PER_WAVE)

__device__ __forceinline__ unsigned long long shfl_xor_u64(unsigned long long v, int m) {
    int lo = __shfl_xor((int)(uint32_t)v, m, 64);
    int hi = __shfl_xor((int)(uint32_t)(v >> 32), m, 64);
    return ((unsigned long long)(uint32_t)hi << 32) | (unsigned long long)(uint32_t)lo;
}

__global__ __launch_bounds__(256, 2)
void router_kernel(const float* __restrict__ x,   // [T,2048]
                   const float* __restrict__ wg,  // [8,2048]
                   const float* __restrict__ gm,  // [8,8]
                   const float* __restrict__ gr,  // [T,8]
                   float* __restrict__ out,       // 2T gates | 2T idx | 8T logits
                   int T, int D)                  // D == 2048, E == 8
{
    const int wave = threadIdx.x >> 6;
    const int lane = threadIdx.x & 63;
    const int t0   = blockIdx.x * TOKENS_PER_BLOCK + wave * TOKENS_PER_WAVE;

    // per-wave reduction scratch: 32 rows x (64+1) floats, bank-conflict-free
    __shared__ float sc_all[WAVES_PER_BLOCK][32 * 65];
    float* sc = sc_all[wave];

    // ---- main GEMM: acc[tt][e] = partial dot over this lane's column slice
    float acc[8][8];
    #pragma unroll
    for (int tt = 0; tt < 8; ++tt)
        #pragma unroll
        for (int e = 0; e < 8; ++e) acc[tt][e] = 0.f;

    const float* xw  = x  + (size_t)t0 * D + lane * 4;
    const float* wgl = wg + lane * 4;

    #pragma unroll
    for (int j = 0; j < 8; ++j) {            // D = 8 chunks of 256 floats
        float4 xf[8];
        #pragma unroll
        for (int tt = 0; tt < 8; ++tt)
            xf[tt] = *(const float4*)(xw + (size_t)tt * D + j * 256);
        #pragma unroll
        for (int e = 0; e < 8; ++e) {
            const float4 wf = *(const float4*)(wgl + (size_t)e * D + j * 256);
            #pragma unroll
            for (int tt = 0; tt < 8; ++tt) {
                acc[tt][e] += xf[tt].x * wf.x;
                acc[tt][e] += xf[tt].y * wf.y;
                acc[tt][e] += xf[tt].z * wf.z;
                acc[tt][e] += xf[tt].w * wf.w;
            }
        }
    }

    // ---- cross-lane reduction: value v = tt*8+e ends fully summed in lane v.
    // Two phases of 32 values; each lane sums half a row then one shfl_xor(32).
    float logit = 0.f;
    #pragma unroll
    for (int ph = 0; ph < 2; ++ph) {
        __syncthreads();   // waves run in lockstep; cheap, guarantees LDS reuse safety
        #pragma unroll
        for (int v = 0; v < 32; ++v) {
            const int vv = ph * 32 + v;
            sc[v * 65 + lane] = acc[vv >> 3][vv & 7];
        }
        __syncthreads();
        const int vrow = lane & 31;         // value row this lane helps reduce
        const int half = lane >> 5;         // which half of the 64 partials
        float r0 = 0.f, r1 = 0.f, r2 = 0.f, r3 = 0.f;
        const float* row = sc + vrow * 65 + half * 32;
        #pragma unroll
        for (int j = 0; j < 32; j += 4) {
            r0 += row[j];
            r1 += row[j + 1];
            r2 += row[j + 2];
            r3 += row[j + 3];
        }
        float h = (r0 + r1) + (r2 + r3);
        h += __shfl_xor(h, 32, 64);         // both lanes vrow, vrow+32 have full sum
        // owner of value (ph*32 + vrow) is lane ph*32 + vrow
        if ((lane >> 5) == ph) logit = h;   // lane = ph*32 + vrow owns it
    }

    // lane v: tt = v>>3 (token), f = v&7 (expert)
    const int tt = lane >> 3;
    const int f  = lane & 7;
    const int t  = t0 + tt;

    // ---- residual: logit[t][f] += sum_e gr[t][e] * gm[f][e]
    const float4 ga = *(const float4*)(gr + (size_t)t * 8);
    const float4 gb = *(const float4*)(gr + (size_t)t * 8 + 4);
    const float4 ma = *(const float4*)(gm + f * 8);
    const float4 mb = *(const float4*)(gm + f * 8 + 4);
    logit += ga.x * ma.x + ga.y * ma.y + ga.z * ma.z + ga.w * ma.w
           + gb.x * mb.x + gb.y * mb.y + gb.z * mb.z + gb.w * mb.w;

    // logits output (offset 4T), contiguous per wave
    out[(size_t)4 * T + (size_t)t0 * 8 + lane] = logit;

    // ---- stats over the 8-lane expert group
    float s = logit;
    s += __shfl_xor(s, 1, 64);
    s += __shfl_xor(s, 2, 64);
    s += __shfl_xor(s, 4, 64);
    const float mean = s * 0.125f;
    float d2 = (logit - mean) * (logit - mean);
    d2 += __shfl_xor(d2, 1, 64);
    d2 += __shfl_xor(d2, 2, 64);
    d2 += __shfl_xor(d2, 4, 64);
    const float stdv = sqrtf(d2 / 7.0f);    // ddof=1

    // ---- top-2 via order-preserving 64-bit keys; ties -> smaller index
    uint32_t ob = __float_as_uint(logit);
    ob = (ob & 0x80000000u) ? ~ob : (ob | 0x80000000u);
    unsigned long long k1 = ((unsigned long long)ob << 8) | (unsigned long long)(7 - f);
    unsigned long long k2 = 0ull;
    #pragma unroll
    for (int m = 1; m <= 4; m <<= 1) {
        const unsigned long long o1 = shfl_xor_u64(k1, m);
        const unsigned long long o2 = shfl_xor_u64(k2, m);
        const unsigned long long hi = k1 > o1 ? k1 : o1;
        const unsigned long long lo = k1 > o1 ? o1 : k1;
        const unsigned long long so = k2 > o2 ? k2 : o2;
        k1 = hi;
        k2 = lo > so ? lo : so;
    }
    const int i1 = 7 - (int)(k1 & 0xFFull);
    const int i2 = 7 - (int)(k2 & 0xFFull);
    uint32_t b1 = (uint32_t)(k1 >> 8), b2 = (uint32_t)(k2 >> 8);
    b1 = (b1 & 0x80000000u) ? (b1 ^ 0x80000000u) : ~b1;
    b2 = (b2 & 0x80000000u) ? (b2 ^ 0x80000000u) : ~b2;
    const float l1 = __uint_as_float(b1);
    const float l2 = __uint_as_float(b2);

    // gates: softmax + zero-expert-7 + renorm collapses to a sigmoid
    float g0, g1;
    if (i1 == 7)      { g0 = 0.f; g1 = 1.f; }
    else if (i2 == 7) { g0 = 1.f; g1 = 0.f; }
    else {
        const float p = 1.0f / (1.0f + __expf(-(l1 - l2) / stdv));
        g0 = p; g1 = 1.0f - p;
    }

    if (f == 0) out[(size_t)2 * t]             = g0;
    if (f == 1) out[(size_t)2 * t + 1]         = g1;
    if (f == 2) out[(size_t)2 * T + 2 * t]     = (float)i1;
    if (f == 3) out[(size_t)2 * T + 2 * t + 1] = (float)i2;
}

extern "C" void kernel_launch(void* const* d_in, const int* in_sizes, int n_in,
                              void* d_out, int out_size, void* d_ws, size_t ws_size,
                              hipStream_t stream) {
    const float* x  = (const float*)d_in[0];
    const float* wg = (const float*)d_in[1];
    const float* gm = (const float*)d_in[2];
    const float* gr = (const float*)d_in[3];
    const int E = 8;
    const int D = in_sizes[1] / E;       // 2048
    const int T = in_sizes[0] / D;       // 16384
    const int blocks = T / TOKENS_PER_BLOCK;   // 512
    router_kernel<<<blocks, 256, 0, stream>>>(x, wg, gm, gr, (float*)d_out, T, D);
}

// Round 2
// 195.371 us; speedup vs baseline: 1.0591x; 1.0591x over previous
//
#include <hip/hip_runtime.h>
#include <hip/hip_bf16.h>
#include <stdint.h>

// Router: logits = x @ wg^T + gr @ gm^T ; std-normalized softmax; top-2;
// zero expert 7; renormalize. Outputs flat: gates[T,2] | indices[T,2] (as
// float) | logits[T,8].  T=16384, D=2048, E=8.
//
// Memory-bound on x (128 MiB fp32, read once). Structure:
//  - wg (64 KB) staged in LDS once per block -> wg reads use lgkmcnt,
//    decoupled from the x-stream's vmcnt (prefetch never drains).
//  - one wave = 8 tokens; lane = 16 B column slice; ping-pong x prefetch
//    keeps 8 x 1 KB loads in flight per wave at all times.
//  - cross-lane reduction: 6-stage butterfly reduce-scatter (no LDS, no
//    syncthreads); lane l ends with logit for token l>>3, expert l&7.

#define WAVES_PER_BLOCK 4
#define TOKENS_PER_WAVE 8
#define TOKENS_PER_BLOCK (WAVES_PER_BLOCK * TOKENS_PER_WAVE)
#define DCONST 2048
#define NCHUNK 8  // DCONST / 256 floats per wave-load

__device__ __forceinline__ unsigned long long shfl_xor_u64(unsigned long long v, int m) {
    int lo = __shfl_xor((int)(uint32_t)v, m, 64);
    int hi = __shfl_xor((int)(uint32_t)(v >> 32), m, 64);
    return ((unsigned long long)(uint32_t)hi << 32) | (unsigned long long)(uint32_t)lo;
}

__global__ __launch_bounds__(256, 2)
void router_kernel(const float* __restrict__ x,   // [T,2048]
                   const float* __restrict__ wg,  // [8,2048]
                   const float* __restrict__ gm,  // [8,8]
                   const float* __restrict__ gr,  // [T,8]
                   float* __restrict__ out,       // 2T gates | 2T idx | 8T logits
                   int T)
{
    const int wave = threadIdx.x >> 6;
    const int lane = threadIdx.x & 63;
    const int t0   = blockIdx.x * TOKENS_PER_BLOCK + wave * TOKENS_PER_WAVE;

    // ---- stage wg into LDS (64 KB), coalesced float4
    __shared__ float swg[8 * DCONST];
    {
        const float4* src = (const float4*)wg;
        float4*       dst = (float4*)swg;
        #pragma unroll
        for (int i = 0; i < 16; ++i)
            dst[threadIdx.x + i * 256] = src[threadIdx.x + i * 256];
    }
    __syncthreads();

    // ---- main GEMM: acc[tt][e] partial dots over this lane's 16 B slices
    float acc[64];
    #pragma unroll
    for (int v = 0; v < 64; ++v) acc[v] = 0.f;

    const float* xw = x + (size_t)t0 * DCONST + (lane << 2);
    const float* wl = swg + (lane << 2);

    float4 xa[8], xb[8];

    #define LOADX(buf, j)                                                     \
        { _Pragma("unroll")                                                   \
          for (int tt = 0; tt < 8; ++tt)                                      \
              buf[tt] = *(const float4*)(xw + tt * DCONST + (j) * 256); }

    #define COMPUTE(j, buf)                                                   \
        { _Pragma("unroll")                                                   \
          for (int e = 0; e < 8; ++e) {                                       \
              const float4 wf = *(const float4*)(wl + e * DCONST + (j) * 256);\
              _Pragma("unroll")                                               \
              for (int tt = 0; tt < 8; ++tt) {                                \
                  acc[tt * 8 + e] += buf[tt].x * wf.x;                        \
                  acc[tt * 8 + e] += buf[tt].y * wf.y;                        \
                  acc[tt * 8 + e] += buf[tt].z * wf.z;                        \
                  acc[tt * 8 + e] += buf[tt].w * wf.w;                        \
              }                                                               \
          } }

    LOADX(xa, 0);
    #pragma unroll 1
    for (int j = 0; j < NCHUNK - 2; j += 2) {
        LOADX(xb, j + 1);
        COMPUTE(j, xa);
        LOADX(xa, j + 2);
        COMPUTE(j + 1, xb);
    }
    LOADX(xb, NCHUNK - 1);
    COMPUTE(NCHUNK - 2, xa);
    COMPUTE(NCHUNK - 1, xb);

    // ---- butterfly reduce-scatter: lane l ends with value l = tt*8+e
    #pragma unroll
    for (int m = 1; m < 64; m <<= 1) {
        const bool up = (lane & m) != 0;
        #pragma unroll
        for (int v = 0; v < 64; v += 2 * m) {
            const float keep = up ? acc[v + m] : acc[v];
            const float send = up ? acc[v] : acc[v + m];
            const float got  = __shfl_xor(send, m, 64);
            acc[v] = keep + got;
        }
    }
    float logit = acc[0];

    const int tt = lane >> 3;
    const int f  = lane & 7;
    const int t  = t0 + tt;

    // ---- residual: logit += sum_e gr[t][e] * gm[f][e]
    const float4 ga = *(const float4*)(gr + (size_t)t * 8);
    const float4 gb = *(const float4*)(gr + (size_t)t * 8 + 4);
    const float4 ma = *(const float4*)(gm + f * 8);
    const float4 mb = *(const float4*)(gm + f * 8 + 4);
    logit += ga.x * ma.x + ga.y * ma.y + ga.z * ma.z + ga.w * ma.w
           + gb.x * mb.x + gb.y * mb.y + gb.z * mb.z + gb.w * mb.w;

    // logits output (offset 4T), contiguous per wave
    out[(size_t)4 * T + (size_t)t0 * 8 + lane] = logit;

    // ---- stats over the 8-lane expert group
    float s = logit;
    s += __shfl_xor(s, 1, 64);
    s += __shfl_xor(s, 2, 64);
    s += __shfl_xor(s, 4, 64);
    const float mean = s * 0.125f;
    float d2 = (logit - mean) * (logit - mean);
    d2 += __shfl_xor(d2, 1, 64);
    d2 += __shfl_xor(d2, 2, 64);
    d2 += __shfl_xor(d2, 4, 64);
    const float stdv = sqrtf(d2 / 7.0f);    // ddof=1

    // ---- top-2 via order-preserving 64-bit keys; ties -> smaller index
    uint32_t ob = __float_as_uint(logit);
    ob = (ob & 0x80000000u) ? ~ob : (ob | 0x80000000u);
    unsigned long long k1 = ((unsigned long long)ob << 8) | (unsigned long long)(7 - f);
    unsigned long long k2 = 0ull;
    #pragma unroll
    for (int m = 1; m <= 4; m <<= 1) {
        const unsigned long long o1 = shfl_xor_u64(k1, m);
        const unsigned long long o2 = shfl_xor_u64(k2, m);
        const unsigned long long hi = k1 > o1 ? k1 : o1;
        const unsigned long long lo = k1 > o1 ? o1 : k1;
        const unsigned long long so = k2 > o2 ? k2 : o2;
        k1 = hi;
        k2 = lo > so ? lo : so;
    }
    const int i1 = 7 - (int)(k1 & 0xFFull);
    const int i2 = 7 - (int)(k2 & 0xFFull);
    uint32_t b1 = (uint32_t)(k1 >> 8), b2 = (uint32_t)(k2 >> 8);
    b1 = (b1 & 0x80000000u) ? (b1 ^ 0x80000000u) : ~b1;
    b2 = (b2 & 0x80000000u) ? (b2 ^ 0x80000000u) : ~b2;
    const float l1 = __uint_as_float(b1);
    const float l2 = __uint_as_float(b2);

    // gates: softmax + zero-expert-7 + renorm collapses to a sigmoid
    float g0, g1;
    if (i1 == 7)      { g0 = 0.f; g1 = 1.f; }
    else if (i2 == 7) { g0 = 1.f; g1 = 0.f; }
    else {
        const float p = 1.0f / (1.0f + __expf(-(l1 - l2) / stdv));
        g0 = p; g1 = 1.0f - p;
    }

    if (f == 0) out[(size_t)2 * t]             = g0;
    if (f == 1) out[(size_t)2 * t + 1]         = g1;
    if (f == 2) out[(size_t)2 * T + 2 * t]     = (float)i1;
    if (f == 3) out[(size_t)2 * T + 2 * t + 1] = (float)i2;
}

extern "C" void kernel_launch(void* const* d_in, const int* in_sizes, int n_in,
                              void* d_out, int out_size, void* d_ws, size_t ws_size,
                              hipStream_t stream) {
    const float* x  = (const float*)d_in[0];
    const float* wg = (const float*)d_in[1];
    const float* gm = (const float*)d_in[2];
    const float* gr = (const float*)d_in[3];
    const int T = in_sizes[0] / DCONST;        // 16384
    const int blocks = T / TOKENS_PER_BLOCK;   // 512
    router_kernel<<<blocks, 256, 0, stream>>>(x, wg, gm, gr, (float*)d_out, T);
}